// Round 1
// baseline (191.899 us; speedup 1.0000x reference)
//
#include <hip/hip_runtime.h>
#include <hip/hip_bf16.h>

// B=2, N=2048, C=1024, H=16, D=64, SCALE=0.125
// out0 = (attn(x)+f) @ W_proj + b_proj ; out1 = attn2gcn
#define OUT1_OFF 4194304
#define QSCALE 0.1803368801111204f   // 0.125 * log2(e)

typedef __attribute__((ext_vector_type(8))) short bf16x8;
typedef __attribute__((ext_vector_type(4))) float f32x4;

__device__ __forceinline__ unsigned short f2bf(float x) {
    unsigned u = __float_as_uint(x);
    u += 0x7FFFu + ((u >> 16) & 1u);
    return (unsigned short)(u >> 16);
}

// async global->LDS, 16B per lane. dst must be base + lane*16 (contiguous).
__device__ __forceinline__ void gl2lds16(const unsigned short* g, unsigned short* l) {
    __builtin_amdgcn_global_load_lds(
        (const __attribute__((address_space(1))) unsigned int*)g,
        (__attribute__((address_space(3))) unsigned int*)l, 16, 0, 0);
}

// ---------------------------------------------------------------------------
// prep: region-branched fused converts (x -> bf16; W_qkv, W_proj -> transposed bf16)
// ---------------------------------------------------------------------------
__global__ __launch_bounds__(256) void prep(const float* __restrict__ x,
                                            const float* __restrict__ Wqkv,
                                            const float* __restrict__ Wproj,
                                            unsigned short* __restrict__ xb,
                                            unsigned short* __restrict__ wqkvT,
                                            unsigned short* __restrict__ wprojT) {
    __shared__ float T[64][65];
    const int bid = blockIdx.x, tid = threadIdx.x;
    if (bid < 4096) {
        int i = bid * 256 + tid;
        float4 v = reinterpret_cast<const float4*>(x)[i];
        ushort4 o = make_ushort4(f2bf(v.x), f2bf(v.y), f2bf(v.z), f2bf(v.w));
        reinterpret_cast<ushort4*>(xb)[i] = o;
        return;
    }
    const float* in; unsigned short* out; int Nd, bx, by;
    if (bid < 4864) { int t = bid - 4096; in = Wqkv;  out = wqkvT;  Nd = 3072; bx = t % 48; by = t / 48; }
    else            { int t = bid - 4864; in = Wproj; out = wprojT; Nd = 1024; bx = t % 16; by = t / 16; }
    const int Kd = 1024;
    const int r0 = by * 64, c0 = bx * 64;
    const int tr = tid >> 3, tc = (tid & 7) * 8;
#pragma unroll
    for (int rr = 0; rr < 64; rr += 32) {
        const float4* p = reinterpret_cast<const float4*>(&in[(r0 + tr + rr) * Nd + c0 + tc]);
        float4 v0 = p[0], v1 = p[1];
        T[tr + rr][tc + 0] = v0.x; T[tr + rr][tc + 1] = v0.y;
        T[tr + rr][tc + 2] = v0.z; T[tr + rr][tc + 3] = v0.w;
        T[tr + rr][tc + 4] = v1.x; T[tr + rr][tc + 5] = v1.y;
        T[tr + rr][tc + 6] = v1.z; T[tr + rr][tc + 7] = v1.w;
    }
    __syncthreads();
#pragma unroll
    for (int rr = 0; rr < 64; rr += 32) {
        int orow = tr + rr;
        ushort4 o0 = make_ushort4(f2bf(T[tc + 0][orow]), f2bf(T[tc + 1][orow]),
                                  f2bf(T[tc + 2][orow]), f2bf(T[tc + 3][orow]));
        ushort4 o1 = make_ushort4(f2bf(T[tc + 4][orow]), f2bf(T[tc + 5][orow]),
                                  f2bf(T[tc + 6][orow]), f2bf(T[tc + 7][orow]));
        unsigned short* dst = &out[(c0 + orow) * Kd + r0 + tc];
        *reinterpret_cast<ushort4*>(dst) = o0;
        *reinterpret_cast<ushort4*>(dst + 4) = o1;
    }
}

// ---------------------------------------------------------------------------
// GEMM1: x(4096,1024) @ WqkvT(3072,1024)^T. 128x128 tile, BK=64, 4 waves 2x2.
// q/k waves swap MFMA operands so the register quad runs along d -> LDS
// transpose (stride-72 scratch, conflict-free) -> fully coalesced uint4 tile
// stores. V same scratch scheme, key-slot permuted to attn's S^T layout.
// ---------------------------------------------------------------------------
__global__ __launch_bounds__(256) void gemm_qkv(const unsigned short* __restrict__ A,
                                                const unsigned short* __restrict__ Bt,
                                                unsigned short* __restrict__ qb,
                                                unsigned short* __restrict__ kb,
                                                unsigned short* __restrict__ vtb) {
    __shared__ __align__(16) unsigned short Sh[18432];   // 36 KB: staging 32K, epi scratch 4x4608
    unsigned short* As = Sh;
    unsigned short* Bs = Sh + 8192;
    const int tid = threadIdx.x;
    const int w = tid >> 6, lane = tid & 63, quad = lane >> 4, l15 = lane & 15;
    const int m0 = blockIdx.y * 128, n0 = blockIdx.x * 128;
    const int wm = (w & 1) * 64, wn = (w >> 1) * 64;
    const int nbase = n0 + wn;
    const int t = nbase >> 10;           // 0=q 1=k 2=v (block-uniform)
    const bool qk = (t < 2);
    const int sw = (l15 & 7) << 3;
    f32x4 acc[4][4] = {};
    for (int k0 = 0; k0 < 1024; k0 += 64) {
        __syncthreads();
#pragma unroll
        for (int tt = 0; tt < 4; ++tt) {
            int c = tt * 256 + tid;
            int row = c >> 3, jg = ((c & 7) ^ (row & 7)) * 8;
            gl2lds16(&A[(m0 + row) * 1024 + k0 + jg], &As[c * 8]);
            gl2lds16(&Bt[(n0 + row) * 1024 + k0 + jg], &Bs[c * 8]);
        }
        __syncthreads();
#pragma unroll
        for (int kk = 0; kk < 2; ++kk) {
            bf16x8 af[4], bfr[4];
#pragma unroll
            for (int i = 0; i < 4; ++i)
                af[i] = *reinterpret_cast<const bf16x8*>(
                    &As[(wm + i * 16 + l15) * 64 + ((((kk * 4 + quad) << 3) ^ sw))]);
#pragma unroll
            for (int j = 0; j < 4; ++j)
                bfr[j] = *reinterpret_cast<const bf16x8*>(
                    &Bs[(wn + j * 16 + l15) * 64 + ((((kk * 4 + quad) << 3) ^ sw))]);
            if (qk) {   // D[row=d, col=tok]
#pragma unroll
                for (int i = 0; i < 4; ++i)
#pragma unroll
                    for (int j = 0; j < 4; ++j)
                        acc[i][j] = __builtin_amdgcn_mfma_f32_16x16x32_bf16(bfr[j], af[i], acc[i][j], 0, 0, 0);
            } else {    // D[row=tok, col=d]
#pragma unroll
                for (int i = 0; i < 4; ++i)
#pragma unroll
                    for (int j = 0; j < 4; ++j)
                        acc[i][j] = __builtin_amdgcn_mfma_f32_16x16x32_bf16(af[i], bfr[j], acc[i][j], 0, 0, 0);
            }
        }
    }
    __syncthreads();                     // staging LDS reusable as scratch
    unsigned short* scr = Sh + w * 4608; // 64 rows x 72 ush (stride 144B, conflict-free)
    const int mb = m0 + wm;
    const int b = mb >> 11;
    const int h = (nbase & 1023) >> 6;
    const float sc = (t == 0) ? QSCALE : 1.f;
    if (qk) {
        // acc[i][j][r]: tok_local = i*16+l15 ; d = j*16+quad*4+r (4 consecutive d)
#pragma unroll
        for (int i = 0; i < 4; ++i) {
            int row = i * 16 + l15;
#pragma unroll
            for (int j = 0; j < 4; ++j) {
                unsigned short h0 = f2bf(acc[i][j][0] * sc), h1 = f2bf(acc[i][j][1] * sc);
                unsigned short h2 = f2bf(acc[i][j][2] * sc), h3 = f2bf(acc[i][j][3] * sc);
                uint2 pk = make_uint2((unsigned)h0 | ((unsigned)h1 << 16),
                                      (unsigned)h2 | ((unsigned)h3 << 16));
                *reinterpret_cast<uint2*>(&scr[row * 72 + j * 16 + quad * 4]) = pk;
            }
        }
        asm volatile("s_waitcnt lgkmcnt(0)" ::: "memory");
        unsigned short* dst = (t == 0 ? qb : kb) + (((b * 16 + h) * 2048) + (mb & 2047)) * 64;
#pragma unroll
        for (int p = 0; p < 8; ++p) {
            int idx = p * 64 + lane;
            *reinterpret_cast<uint4*>(&dst[idx * 8]) =
                *reinterpret_cast<const uint4*>(&scr[(idx >> 3) * 72 + (idx & 7) * 8]);
        }
    } else {
        // V: scratch [d][slot], slot = key permutation matching attn S^T layout
        const int kblk = (mb & 2047) >> 6;
#pragma unroll
        for (int i = 0; i < 4; ++i) {
            int slot0 = ((i & 2) << 4) | (quad << 3) | ((i & 1) << 2);
#pragma unroll
            for (int j = 0; j < 4; ++j) {
                unsigned short h0 = f2bf(acc[i][j][0]), h1 = f2bf(acc[i][j][1]);
                unsigned short h2 = f2bf(acc[i][j][2]), h3 = f2bf(acc[i][j][3]);
                uint2 pk = make_uint2((unsigned)h0 | ((unsigned)h1 << 16),
                                      (unsigned)h2 | ((unsigned)h3 << 16));
                *reinterpret_cast<uint2*>(&scr[(j * 16 + l15) * 72 + slot0]) = pk;
            }
        }
        asm volatile("s_waitcnt lgkmcnt(0)" ::: "memory");
        unsigned short* vtile = vtb + (((b * 16 + h) * 32) + kblk) * 4096;
#pragma unroll
        for (int p = 0; p < 8; ++p) {
            int idx = p * 64 + lane;
            *reinterpret_cast<uint4*>(&vtile[idx * 8]) =
                *reinterpret_cast<const uint4*>(&scr[(idx >> 3) * 72 + (idx & 7) * 8]);
        }
    }
}

// ---------------------------------------------------------------------------
// Attention v6: grid (32 bh, 16 qtiles) = 512 blocks, 4 waves x 32 q = 128 q.
// 32 q/wave halves LDS-read bytes per MFMA FLOP (K/V fragments reused across
// two q-halves held in registers). S^T = K·Q^T; sums via ones-MFMA.
// Double-buffered K/V, setprio around MFMA clusters. LDS 32 KB.
// ---------------------------------------------------------------------------
__global__ __launch_bounds__(256) void attn_kernel(const unsigned short* __restrict__ qb,
                                                   const unsigned short* __restrict__ kb,
                                                   const unsigned short* __restrict__ vtb,
                                                   const float* __restrict__ f,
                                                   float* __restrict__ attn2_out,
                                                   unsigned short* __restrict__ fusedb) {
    __shared__ __align__(16) unsigned short Ksw[2][4096];
    __shared__ __align__(16) unsigned short Vsw[2][4096];
    const int tid = threadIdx.x;
    const int w = tid >> 6, lane = tid & 63, quad = lane >> 4, l15 = lane & 15;
    const int bh = blockIdx.x;          // bh mod 8 = XCD -> K/V L2-resident per XCD
    const int q0 = blockIdx.y * 128 + w * 32;
    const unsigned short* qr = &qb[(bh * 2048 + q0 + l15) * 64 + quad * 8];
    bf16x8 ql0 = *reinterpret_cast<const bf16x8*>(qr);
    bf16x8 ql1 = *reinterpret_cast<const bf16x8*>(qr + 32);
    bf16x8 ql2 = *reinterpret_cast<const bf16x8*>(qr + 1024);   // q-half 1: +16 rows
    bf16x8 ql3 = *reinterpret_cast<const bf16x8*>(qr + 1056);
    const unsigned short* kt0 = kb + bh * 131072;
    const unsigned short* vt0 = vtb + bh * 131072;
    const int c0i = tid, c1i = tid + 256;
    const int gu0 = (((c0i & ~7) | ((c0i & 7) ^ ((c0i >> 3) & 7))) << 3);
    const int gu1 = (((c1i & ~7) | ((c1i & 7) ^ ((c1i >> 3) & 7))) << 3);
    const int sw = (l15 & 7) << 3;
    f32x4 O0[4] = {}, O1[4] = {};
    f32x4 asum0 = {}, asum1 = {};
    bf16x8 ones;
#pragma unroll
    for (int j = 0; j < 8; ++j) ones[j] = (short)0x3F80;   // bf16 1.0

#define STAGE(IT, BUF) do { int _toff = (IT) * 4096;                    \
        gl2lds16(kt0 + _toff + gu0, &Ksw[BUF][c0i * 8]);                \
        gl2lds16(vt0 + _toff + gu0, &Vsw[BUF][c0i * 8]);                \
        gl2lds16(kt0 + _toff + gu1, &Ksw[BUF][c1i * 8]);                \
        gl2lds16(vt0 + _toff + gu1, &Vsw[BUF][c1i * 8]); } while (0)

    auto body = [&](int buf) {
        f32x4 Ta[4], Tb[4];
        __builtin_amdgcn_s_setprio(1);
#pragma unroll
        for (int s = 0; s < 4; ++s) {
            const unsigned short* kr = &Ksw[buf][(s * 16 + l15) * 64];
            bf16x8 k0 = *reinterpret_cast<const bf16x8*>(&kr[(quad << 3) ^ sw]);
            bf16x8 k1 = *reinterpret_cast<const bf16x8*>(&kr[((quad + 4) << 3) ^ sw]);
            f32x4 za = {}, zb = {};
            za = __builtin_amdgcn_mfma_f32_16x16x32_bf16(k0, ql0, za, 0, 0, 0);
            za = __builtin_amdgcn_mfma_f32_16x16x32_bf16(k1, ql1, za, 0, 0, 0);
            zb = __builtin_amdgcn_mfma_f32_16x16x32_bf16(k0, ql2, zb, 0, 0, 0);
            zb = __builtin_amdgcn_mfma_f32_16x16x32_bf16(k1, ql3, zb, 0, 0, 0);
            Ta[s] = za; Tb[s] = zb;
        }
        __builtin_amdgcn_s_setprio(0);
        float pa_[4][4], pb_[4][4];
#pragma unroll
        for (int s = 0; s < 4; ++s)
#pragma unroll
            for (int r = 0; r < 4; ++r) {
                pa_[s][r] = __builtin_amdgcn_exp2f(Ta[s][r]);
                pb_[s][r] = __builtin_amdgcn_exp2f(Tb[s][r]);
            }
        uint4 u0, u1, v0u, v1u;
        u0.x = __builtin_amdgcn_perm(__float_as_uint(pa_[0][1]), __float_as_uint(pa_[0][0]), 0x07060302u);
        u0.y = __builtin_amdgcn_perm(__float_as_uint(pa_[0][3]), __float_as_uint(pa_[0][2]), 0x07060302u);
        u0.z = __builtin_amdgcn_perm(__float_as_uint(pa_[1][1]), __float_as_uint(pa_[1][0]), 0x07060302u);
        u0.w = __builtin_amdgcn_perm(__float_as_uint(pa_[1][3]), __float_as_uint(pa_[1][2]), 0x07060302u);
        u1.x = __builtin_amdgcn_perm(__float_as_uint(pa_[2][1]), __float_as_uint(pa_[2][0]), 0x07060302u);
        u1.y = __builtin_amdgcn_perm(__float_as_uint(pa_[2][3]), __float_as_uint(pa_[2][2]), 0x07060302u);
        u1.z = __builtin_amdgcn_perm(__float_as_uint(pa_[3][1]), __float_as_uint(pa_[3][0]), 0x07060302u);
        u1.w = __builtin_amdgcn_perm(__float_as_uint(pa_[3][3]), __float_as_uint(pa_[3][2]), 0x07060302u);
        v0u.x = __builtin_amdgcn_perm(__float_as_uint(pb_[0][1]), __float_as_uint(pb_[0][0]), 0x07060302u);
        v0u.y = __builtin_amdgcn_perm(__float_as_uint(pb_[0][3]), __float_as_uint(pb_[0][2]), 0x07060302u);
        v0u.z = __builtin_amdgcn_perm(__float_as_uint(pb_[1][1]), __float_as_uint(pb_[1][0]), 0x07060302u);
        v0u.w = __builtin_amdgcn_perm(__float_as_uint(pb_[1][3]), __float_as_uint(pb_[1][2]), 0x07060302u);
        v1u.x = __builtin_amdgcn_perm(__float_as_uint(pb_[2][1]), __float_as_uint(pb_[2][0]), 0x07060302u);
        v1u.y = __builtin_amdgcn_perm(__float_as_uint(pb_[2][3]), __float_as_uint(pb_[2][2]), 0x07060302u);
        v1u.z = __builtin_amdgcn_perm(__float_as_uint(pb_[3][1]), __float_as_uint(pb_[3][0]), 0x07060302u);
        v1u.w = __builtin_amdgcn_perm(__float_as_uint(pb_[3][3]), __float_as_uint(pb_[3][2]), 0x07060302u);
        bf16x8 paa0 = __builtin_bit_cast(bf16x8, u0);
        bf16x8 paa1 = __builtin_bit_cast(bf16x8, u1);
        bf16x8 pba0 = __builtin_bit_cast(bf16x8, v0u);
        bf16x8 pba1 = __builtin_bit_cast(bf16x8, v1u);
        asum0 = __builtin_amdgcn_mfma_f32_16x16x32_bf16(paa0, ones, asum0, 0, 0, 0);
        asum0 = __builtin_amdgcn_mfma_f32_16x16x32_bf16(paa1, ones, asum0, 0, 0, 0);
        asum1 = __builtin_amdgcn_mfma_f32_16x16x32_bf16(pba0, ones, asum1, 0, 0, 0);
        asum1 = __builtin_amdgcn_mfma_f32_16x16x32_bf16(pba1, ones, asum1, 0, 0, 0);
        __builtin_amdgcn_s_setprio(1);
#pragma unroll
        for (int c4 = 0; c4 < 4; ++c4) {
            const unsigned short* vr = &Vsw[buf][(c4 * 16 + l15) * 64];
            bf16x8 v0 = *reinterpret_cast<const bf16x8*>(&vr[(quad << 3) ^ sw]);
            bf16x8 v1 = *reinterpret_cast<const bf16x8*>(&vr[((quad + 4) << 3) ^ sw]);
            O0[c4] = __builtin_amdgcn_mfma_f32_16x16x32_bf16(paa0, v0, O0[c4], 0, 0, 0);
            O0[c4] = __builtin_amdgcn_mfma_f32_16x16x32_bf16(paa1, v1, O0[c4], 0, 0, 0);
            O1[c4] = __builtin_amdgcn_mfma_f32_16x16x32_bf16(pba0, v0, O1[c4], 0, 0, 0);
            O1[c4] = __builtin_amdgcn_mfma_f32_16x16x32_bf16(pba1, v1, O1[c4], 0, 0, 0);
        }
        __builtin_amdgcn_s_setprio(0);
    };

    STAGE(0, 0);
    for (int it = 0; it < 32; it += 2) {
        __syncthreads();                 // buf0 staged; prior buf1 reads done
        STAGE(it + 1, 1);
        body(0);
        __syncthreads();                 // buf1 staged; buf0 reads done
        if (it + 2 < 32) STAGE(it + 2, 0);
        body(1);
    }
#undef STAGE

    const int b = bh >> 4, h = bh & 15;
#pragma unroll
    for (int r = 0; r < 4; ++r) {
        float inv0 = 1.f / asum0[r];
        float inv1 = 1.f / asum1[r];
        int tok0 = q0 + quad * 4 + r;
        int base0 = (b * 2048 + tok0) * 1024 + h * 64;
        int base1 = base0 + 16 * 1024;   // q-half 1: +16 tokens
#pragma unroll
        for (int c4 = 0; c4 < 4; ++c4) {
            int col = c4 * 16 + l15;
            float o0 = O0[c4][r] * inv0;
            attn2_out[base0 + col] = o0;
            fusedb[base0 + col] = f2bf(o0 + f[base0 + col]);
            float o1 = O1[c4][r] * inv1;
            attn2_out[base1 + col] = o1;
            fusedb[base1 + col] = f2bf(o1 + f[base1 + col]);
        }
    }
}

// ---------------------------------------------------------------------------
// GEMM2: fused(4096,1024) @ WprojT(1024,1024)^T + bias. 128x64 tile,
// grid (16,32)=512 -> 2 blocks/CU, wave 64x32.
// ---------------------------------------------------------------------------
__global__ __launch_bounds__(256) void gemm_proj(const unsigned short* __restrict__ A,
                                                 const unsigned short* __restrict__ Bt,
                                                 const float* __restrict__ bias,
                                                 float* __restrict__ out) {
    __shared__ __align__(16) unsigned short As[8192];
    __shared__ __align__(16) unsigned short Bs[4096];
    const int tid = threadIdx.x;
    const int w = tid >> 6, lane = tid & 63, quad = lane >> 4, l15 = lane & 15;
    const int m0 = blockIdx.y * 128, n0 = blockIdx.x * 64;
    const int wm = (w & 1) * 64, wn = (w >> 1) * 32;
    const int sw = (l15 & 7) << 3;
    f32x4 acc[4][2] = {};
    for (int k0 = 0; k0 < 1024; k0 += 64) {
        __syncthreads();
#pragma unroll
        for (int t = 0; t < 4; ++t) {
            int c = t * 256 + tid;
            int row = c >> 3, jg = ((c & 7) ^ (row & 7)) * 8;
            gl2lds16(&A[(m0 + row) * 1024 + k0 + jg], &As[c * 8]);
            if (t < 2) gl2lds16(&Bt[(n0 + row) * 1024 + k0 + jg], &Bs[c * 8]);
        }
        __syncthreads();
#pragma unroll
        for (int kk = 0; kk < 2; ++kk) {
            bf16x8 af[4], bfr[2];
#pragma unroll
            for (int i = 0; i < 4; ++i)
                af[i] = *reinterpret_cast<const bf16x8*>(
                    &As[(wm + i * 16 + l15) * 64 + ((((kk * 4 + quad) << 3) ^ sw))]);
#pragma unroll
            for (int j = 0; j < 2; ++j)
                bfr[j] = *reinterpret_cast<const bf16x8*>(
                    &Bs[(wn + j * 16 + l15) * 64 + ((((kk * 4 + quad) << 3) ^ sw))]);
#pragma unroll
            for (int i = 0; i < 4; ++i)
#pragma unroll
                for (int j = 0; j < 2; ++j)
                    acc[i][j] = __builtin_amdgcn_mfma_f32_16x16x32_bf16(af[i], bfr[j], acc[i][j], 0, 0, 0);
        }
    }
#pragma unroll
    for (int j = 0; j < 2; ++j) {
        int n = n0 + wn + j * 16 + l15;
        float bv = bias[n];
#pragma unroll
        for (int i = 0; i < 4; ++i)
#pragma unroll
            for (int r = 0; r < 4; ++r) {
                int m = m0 + wm + i * 16 + quad * 4 + r;
                out[m * 1024 + n] = acc[i][j][r] + bv;
            }
    }
}

extern "C" void kernel_launch(void* const* d_in, const int* in_sizes, int n_in,
                              void* d_out, int out_size, void* d_ws, size_t ws_size,
                              hipStream_t stream) {
    const float* x      = (const float*)d_in[0];
    const float* f      = (const float*)d_in[1];
    const float* W_qkv  = (const float*)d_in[2];
    const float* W_proj = (const float*)d_in[3];
    const float* b_proj = (const float*)d_in[4];
    float* out   = (float*)d_out;
    float* attn2 = out + OUT1_OFF;

    char* ws = (char*)d_ws;
    unsigned short* xb     = (unsigned short*)(ws);                 //  8 MiB
    unsigned short* wqkvT  = (unsigned short*)(ws + 8388608);       //  6 MiB (3072,1024)
    unsigned short* wprojT = (unsigned short*)(ws + 14680064);      //  2 MiB (1024,1024)
    unsigned short* qb     = (unsigned short*)(ws + 16777216);      //  8 MiB (B,H,N,D)
    unsigned short* kb     = (unsigned short*)(ws + 25165824);      //  8 MiB (B,H,N,D)
    unsigned short* vtb    = (unsigned short*)(ws + 33554432);      //  8 MiB (B,H,kblk,D,slot)
    unsigned short* fusedb = (unsigned short*)(ws + 41943040);      //  8 MiB (B*N,C)

    prep<<<5120, 256, 0, stream>>>(x, W_qkv, W_proj, xb, wqkvT, wprojT);
    gemm_qkv<<<dim3(24, 32), 256, 0, stream>>>(xb, wqkvT, qb, kb, vtb);
    attn_kernel<<<dim3(32, 16), 256, 0, stream>>>(qb, kb, vtb, f, attn2, fusedb);
    gemm_proj<<<dim3(16, 32), 256, 0, stream>>>(fusedb, wprojT, b_proj, out);
}

// Round 2
// 187.038 us; speedup vs baseline: 1.0260x; 1.0260x over previous
//
#include <hip/hip_runtime.h>
#include <hip/hip_bf16.h>

// B=2, N=2048, C=1024, H=16, D=64, SCALE=0.125
// out0 = (attn(x)+f) @ W_proj + b_proj ; out1 = attn2gcn
#define OUT1_OFF 4194304
#define QSCALE 0.1803368801111204f   // 0.125 * log2(e)

typedef __attribute__((ext_vector_type(8))) short bf16x8;
typedef __attribute__((ext_vector_type(4))) float f32x4;

__device__ __forceinline__ unsigned short f2bf(float x) {
    unsigned u = __float_as_uint(x);
    u += 0x7FFFu + ((u >> 16) & 1u);
    return (unsigned short)(u >> 16);
}

// async global->LDS, 16B per lane. dst must be base + lane*16 (contiguous).
__device__ __forceinline__ void gl2lds16(const unsigned short* g, unsigned short* l) {
    __builtin_amdgcn_global_load_lds(
        (const __attribute__((address_space(1))) unsigned int*)g,
        (__attribute__((address_space(3))) unsigned int*)l, 16, 0, 0);
}

// ---------------------------------------------------------------------------
// prep: region-branched fused converts (x -> bf16; W_qkv, W_proj -> transposed bf16)
// ---------------------------------------------------------------------------
__global__ __launch_bounds__(256) void prep(const float* __restrict__ x,
                                            const float* __restrict__ Wqkv,
                                            const float* __restrict__ Wproj,
                                            unsigned short* __restrict__ xb,
                                            unsigned short* __restrict__ wqkvT,
                                            unsigned short* __restrict__ wprojT) {
    __shared__ float T[64][65];
    const int bid = blockIdx.x, tid = threadIdx.x;
    if (bid < 4096) {
        int i = bid * 256 + tid;
        float4 v = reinterpret_cast<const float4*>(x)[i];
        ushort4 o = make_ushort4(f2bf(v.x), f2bf(v.y), f2bf(v.z), f2bf(v.w));
        reinterpret_cast<ushort4*>(xb)[i] = o;
        return;
    }
    const float* in; unsigned short* out; int Nd, bx, by;
    if (bid < 4864) { int t = bid - 4096; in = Wqkv;  out = wqkvT;  Nd = 3072; bx = t % 48; by = t / 48; }
    else            { int t = bid - 4864; in = Wproj; out = wprojT; Nd = 1024; bx = t % 16; by = t / 16; }
    const int Kd = 1024;
    const int r0 = by * 64, c0 = bx * 64;
    const int tr = tid >> 3, tc = (tid & 7) * 8;
#pragma unroll
    for (int rr = 0; rr < 64; rr += 32) {
        const float4* p = reinterpret_cast<const float4*>(&in[(r0 + tr + rr) * Nd + c0 + tc]);
        float4 v0 = p[0], v1 = p[1];
        T[tr + rr][tc + 0] = v0.x; T[tr + rr][tc + 1] = v0.y;
        T[tr + rr][tc + 2] = v0.z; T[tr + rr][tc + 3] = v0.w;
        T[tr + rr][tc + 4] = v1.x; T[tr + rr][tc + 5] = v1.y;
        T[tr + rr][tc + 6] = v1.z; T[tr + rr][tc + 7] = v1.w;
    }
    __syncthreads();
#pragma unroll
    for (int rr = 0; rr < 64; rr += 32) {
        int orow = tr + rr;
        ushort4 o0 = make_ushort4(f2bf(T[tc + 0][orow]), f2bf(T[tc + 1][orow]),
                                  f2bf(T[tc + 2][orow]), f2bf(T[tc + 3][orow]));
        ushort4 o1 = make_ushort4(f2bf(T[tc + 4][orow]), f2bf(T[tc + 5][orow]),
                                  f2bf(T[tc + 6][orow]), f2bf(T[tc + 7][orow]));
        unsigned short* dst = &out[(c0 + orow) * Kd + r0 + tc];
        *reinterpret_cast<ushort4*>(dst) = o0;
        *reinterpret_cast<ushort4*>(dst + 4) = o1;
    }
}

// ---------------------------------------------------------------------------
// GEMM1: x(4096,1024) @ WqkvT(3072,1024)^T. 128x128 tile, BK=64, 4 waves 2x2.
// q/k waves swap MFMA operands so the register quad runs along d -> LDS
// transpose (stride-72 scratch, conflict-free) -> fully coalesced uint4 tile
// stores. V same scratch scheme, key-slot permuted to attn's S^T layout.
// ---------------------------------------------------------------------------
__global__ __launch_bounds__(256) void gemm_qkv(const unsigned short* __restrict__ A,
                                                const unsigned short* __restrict__ Bt,
                                                unsigned short* __restrict__ qb,
                                                unsigned short* __restrict__ kb,
                                                unsigned short* __restrict__ vtb) {
    __shared__ __align__(16) unsigned short Sh[18432];   // 36 KB: staging 32K, epi scratch 4x4608
    unsigned short* As = Sh;
    unsigned short* Bs = Sh + 8192;
    const int tid = threadIdx.x;
    const int w = tid >> 6, lane = tid & 63, quad = lane >> 4, l15 = lane & 15;
    const int m0 = blockIdx.y * 128, n0 = blockIdx.x * 128;
    const int wm = (w & 1) * 64, wn = (w >> 1) * 64;
    const int nbase = n0 + wn;
    const int t = nbase >> 10;           // 0=q 1=k 2=v (block-uniform)
    const bool qk = (t < 2);
    const int sw = (l15 & 7) << 3;
    f32x4 acc[4][4] = {};
    for (int k0 = 0; k0 < 1024; k0 += 64) {
        __syncthreads();
#pragma unroll
        for (int tt = 0; tt < 4; ++tt) {
            int c = tt * 256 + tid;
            int row = c >> 3, jg = ((c & 7) ^ (row & 7)) * 8;
            gl2lds16(&A[(m0 + row) * 1024 + k0 + jg], &As[c * 8]);
            gl2lds16(&Bt[(n0 + row) * 1024 + k0 + jg], &Bs[c * 8]);
        }
        __syncthreads();
#pragma unroll
        for (int kk = 0; kk < 2; ++kk) {
            bf16x8 af[4], bfr[4];
#pragma unroll
            for (int i = 0; i < 4; ++i)
                af[i] = *reinterpret_cast<const bf16x8*>(
                    &As[(wm + i * 16 + l15) * 64 + ((((kk * 4 + quad) << 3) ^ sw))]);
#pragma unroll
            for (int j = 0; j < 4; ++j)
                bfr[j] = *reinterpret_cast<const bf16x8*>(
                    &Bs[(wn + j * 16 + l15) * 64 + ((((kk * 4 + quad) << 3) ^ sw))]);
            if (qk) {   // D[row=d, col=tok]
#pragma unroll
                for (int i = 0; i < 4; ++i)
#pragma unroll
                    for (int j = 0; j < 4; ++j)
                        acc[i][j] = __builtin_amdgcn_mfma_f32_16x16x32_bf16(bfr[j], af[i], acc[i][j], 0, 0, 0);
            } else {    // D[row=tok, col=d]
#pragma unroll
                for (int i = 0; i < 4; ++i)
#pragma unroll
                    for (int j = 0; j < 4; ++j)
                        acc[i][j] = __builtin_amdgcn_mfma_f32_16x16x32_bf16(af[i], bfr[j], acc[i][j], 0, 0, 0);
            }
        }
    }
    __syncthreads();                     // staging LDS reusable as scratch
    unsigned short* scr = Sh + w * 4608; // 64 rows x 72 ush (stride 144B, conflict-free)
    const int mb = m0 + wm;
    const int b = mb >> 11;
    const int h = (nbase & 1023) >> 6;
    const float sc = (t == 0) ? QSCALE : 1.f;
    if (qk) {
        // acc[i][j][r]: tok_local = i*16+l15 ; d = j*16+quad*4+r (4 consecutive d)
#pragma unroll
        for (int i = 0; i < 4; ++i) {
            int row = i * 16 + l15;
#pragma unroll
            for (int j = 0; j < 4; ++j) {
                unsigned short h0 = f2bf(acc[i][j][0] * sc), h1 = f2bf(acc[i][j][1] * sc);
                unsigned short h2 = f2bf(acc[i][j][2] * sc), h3 = f2bf(acc[i][j][3] * sc);
                uint2 pk = make_uint2((unsigned)h0 | ((unsigned)h1 << 16),
                                      (unsigned)h2 | ((unsigned)h3 << 16));
                *reinterpret_cast<uint2*>(&scr[row * 72 + j * 16 + quad * 4]) = pk;
            }
        }
        asm volatile("s_waitcnt lgkmcnt(0)" ::: "memory");
        unsigned short* dst = (t == 0 ? qb : kb) + (((b * 16 + h) * 2048) + (mb & 2047)) * 64;
#pragma unroll
        for (int p = 0; p < 8; ++p) {
            int idx = p * 64 + lane;
            *reinterpret_cast<uint4*>(&dst[idx * 8]) =
                *reinterpret_cast<const uint4*>(&scr[(idx >> 3) * 72 + (idx & 7) * 8]);
        }
    } else {
        // V: scratch [d][slot], slot = key permutation matching attn S^T layout
        const int kblk = (mb & 2047) >> 6;
#pragma unroll
        for (int i = 0; i < 4; ++i) {
            int slot0 = ((i & 2) << 4) | (quad << 3) | ((i & 1) << 2);
#pragma unroll
            for (int j = 0; j < 4; ++j) {
                unsigned short h0 = f2bf(acc[i][j][0]), h1 = f2bf(acc[i][j][1]);
                unsigned short h2 = f2bf(acc[i][j][2]), h3 = f2bf(acc[i][j][3]);
                uint2 pk = make_uint2((unsigned)h0 | ((unsigned)h1 << 16),
                                      (unsigned)h2 | ((unsigned)h3 << 16));
                *reinterpret_cast<uint2*>(&scr[(j * 16 + l15) * 72 + slot0]) = pk;
            }
        }
        asm volatile("s_waitcnt lgkmcnt(0)" ::: "memory");
        unsigned short* vtile = vtb + (((b * 16 + h) * 32) + kblk) * 4096;
#pragma unroll
        for (int p = 0; p < 8; ++p) {
            int idx = p * 64 + lane;
            *reinterpret_cast<uint4*>(&vtile[idx * 8]) =
                *reinterpret_cast<const uint4*>(&scr[(idx >> 3) * 72 + (idx & 7) * 8]);
        }
    }
}

// ---------------------------------------------------------------------------
// Attention v7: grid (32 bh, 16 qtiles) = 512 blocks, 512 thr = 8 waves,
// organized as 4 q-groups x 2 K-halves. Each wave: 32 q rows x 16 K-tiles.
// -> per-wave LDS-read bytes HALVED vs v5 at v5's 16 waves/CU occupancy.
// No-max softmax (pure exp2-sum) => K-halves combine by simple addition in
// LDS scratch (staging buffers reused, 68 KB). Double-buffered staging of
// 4 tiles/step (K,V for both halves). LDS 68 KB -> 2 blocks/CU.
// ---------------------------------------------------------------------------
__global__ __launch_bounds__(512, 4) void attn_kernel(const unsigned short* __restrict__ qb,
                                                      const unsigned short* __restrict__ kb,
                                                      const unsigned short* __restrict__ vtb,
                                                      const float* __restrict__ f,
                                                      float* __restrict__ attn2_out,
                                                      unsigned short* __restrict__ fusedb) {
    __shared__ __align__(16) unsigned char SMEM[69632];  // staging 64K | scratch 8x(32x68 f32)
    unsigned short* S16 = reinterpret_cast<unsigned short*>(SMEM);
    const int tid = threadIdx.x;
    const int w = tid >> 6, lane = tid & 63, quad = lane >> 4, l15 = lane & 15;
    const int qg = w & 3, kh = w >> 2;   // q-group 0..3, K-half 0..1
    const int bh = blockIdx.x;           // bh mod 8 = XCD -> K/V L2-resident per XCD
    const int q0w = blockIdx.y * 128 + qg * 32;
    const unsigned short* qr = &qb[(bh * 2048 + q0w + l15) * 64 + quad * 8];
    bf16x8 ql0 = *reinterpret_cast<const bf16x8*>(qr);
    bf16x8 ql1 = *reinterpret_cast<const bf16x8*>(qr + 32);
    bf16x8 ql2 = *reinterpret_cast<const bf16x8*>(qr + 1024);   // q-half 1: +16 rows
    bf16x8 ql3 = *reinterpret_cast<const bf16x8*>(qr + 1056);
    const unsigned short* kt0 = kb + bh * 131072;
    const unsigned short* vt0 = vtb + bh * 131072;
    const int gu = (((tid & ~7) | ((tid & 7) ^ ((tid >> 3) & 7))) << 3);
    const int sw = (l15 & 7) << 3;
    f32x4 O0[4] = {}, O1[4] = {};
    f32x4 asum0 = {}, asum1 = {};
    bf16x8 ones;
#pragma unroll
    for (int j = 0; j < 8; ++j) ones[j] = (short)0x3F80;   // bf16 1.0

    // stage K,V tiles (IT) for half0 and (16+IT) for half1 into buffer BUF.
    // layout per buf (16384 ush): [K h0][V h0][K h1][V h1], 4096 ush each.
#define STAGE(IT, BUF) do { unsigned short* db_ = &S16[(BUF) * 16384 + tid * 8]; \
        const int go_ = (IT) * 4096 + gu;                                        \
        gl2lds16(kt0 + go_, db_);                                                \
        gl2lds16(vt0 + go_, db_ + 4096);                                         \
        gl2lds16(kt0 + 65536 + go_, db_ + 8192);                                 \
        gl2lds16(vt0 + 65536 + go_, db_ + 12288); } while (0)

    auto body = [&](int buf) {
        const unsigned short* Kb = &S16[buf * 16384 + kh * 8192];
        const unsigned short* Vb = Kb + 4096;
        f32x4 Ta[4], Tb[4];
        __builtin_amdgcn_s_setprio(1);
#pragma unroll
        for (int s = 0; s < 4; ++s) {
            const unsigned short* kr = &Kb[(s * 16 + l15) * 64];
            bf16x8 k0 = *reinterpret_cast<const bf16x8*>(&kr[(quad << 3) ^ sw]);
            bf16x8 k1 = *reinterpret_cast<const bf16x8*>(&kr[((quad + 4) << 3) ^ sw]);
            f32x4 za = {}, zb = {};
            za = __builtin_amdgcn_mfma_f32_16x16x32_bf16(k0, ql0, za, 0, 0, 0);
            za = __builtin_amdgcn_mfma_f32_16x16x32_bf16(k1, ql1, za, 0, 0, 0);
            zb = __builtin_amdgcn_mfma_f32_16x16x32_bf16(k0, ql2, zb, 0, 0, 0);
            zb = __builtin_amdgcn_mfma_f32_16x16x32_bf16(k1, ql3, zb, 0, 0, 0);
            Ta[s] = za; Tb[s] = zb;
        }
        __builtin_amdgcn_s_setprio(0);
        float pa_[4][4], pb_[4][4];
#pragma unroll
        for (int s = 0; s < 4; ++s)
#pragma unroll
            for (int r = 0; r < 4; ++r) {
                pa_[s][r] = __builtin_amdgcn_exp2f(Ta[s][r]);
                pb_[s][r] = __builtin_amdgcn_exp2f(Tb[s][r]);
            }
        uint4 u0, u1, v0u, v1u;
        u0.x = __builtin_amdgcn_perm(__float_as_uint(pa_[0][1]), __float_as_uint(pa_[0][0]), 0x07060302u);
        u0.y = __builtin_amdgcn_perm(__float_as_uint(pa_[0][3]), __float_as_uint(pa_[0][2]), 0x07060302u);
        u0.z = __builtin_amdgcn_perm(__float_as_uint(pa_[1][1]), __float_as_uint(pa_[1][0]), 0x07060302u);
        u0.w = __builtin_amdgcn_perm(__float_as_uint(pa_[1][3]), __float_as_uint(pa_[1][2]), 0x07060302u);
        u1.x = __builtin_amdgcn_perm(__float_as_uint(pa_[2][1]), __float_as_uint(pa_[2][0]), 0x07060302u);
        u1.y = __builtin_amdgcn_perm(__float_as_uint(pa_[2][3]), __float_as_uint(pa_[2][2]), 0x07060302u);
        u1.z = __builtin_amdgcn_perm(__float_as_uint(pa_[3][1]), __float_as_uint(pa_[3][0]), 0x07060302u);
        u1.w = __builtin_amdgcn_perm(__float_as_uint(pa_[3][3]), __float_as_uint(pa_[3][2]), 0x07060302u);
        v0u.x = __builtin_amdgcn_perm(__float_as_uint(pb_[0][1]), __float_as_uint(pb_[0][0]), 0x07060302u);
        v0u.y = __builtin_amdgcn_perm(__float_as_uint(pb_[0][3]), __float_as_uint(pb_[0][2]), 0x07060302u);
        v0u.z = __builtin_amdgcn_perm(__float_as_uint(pb_[1][1]), __float_as_uint(pb_[1][0]), 0x07060302u);
        v0u.w = __builtin_amdgcn_perm(__float_as_uint(pb_[1][3]), __float_as_uint(pb_[1][2]), 0x07060302u);
        v1u.x = __builtin_amdgcn_perm(__float_as_uint(pb_[2][1]), __float_as_uint(pb_[2][0]), 0x07060302u);
        v1u.y = __builtin_amdgcn_perm(__float_as_uint(pb_[2][3]), __float_as_uint(pb_[2][2]), 0x07060302u);
        v1u.z = __builtin_amdgcn_perm(__float_as_uint(pb_[3][1]), __float_as_uint(pb_[3][0]), 0x07060302u);
        v1u.w = __builtin_amdgcn_perm(__float_as_uint(pb_[3][3]), __float_as_uint(pb_[3][2]), 0x07060302u);
        bf16x8 paa0 = __builtin_bit_cast(bf16x8, u0);
        bf16x8 paa1 = __builtin_bit_cast(bf16x8, u1);
        bf16x8 pba0 = __builtin_bit_cast(bf16x8, v0u);
        bf16x8 pba1 = __builtin_bit_cast(bf16x8, v1u);
        asum0 = __builtin_amdgcn_mfma_f32_16x16x32_bf16(paa0, ones, asum0, 0, 0, 0);
        asum0 = __builtin_amdgcn_mfma_f32_16x16x32_bf16(paa1, ones, asum0, 0, 0, 0);
        asum1 = __builtin_amdgcn_mfma_f32_16x16x32_bf16(pba0, ones, asum1, 0, 0, 0);
        asum1 = __builtin_amdgcn_mfma_f32_16x16x32_bf16(pba1, ones, asum1, 0, 0, 0);
        __builtin_amdgcn_s_setprio(1);
#pragma unroll
        for (int c4 = 0; c4 < 4; ++c4) {
            const unsigned short* vr = &Vb[(c4 * 16 + l15) * 64];
            bf16x8 v0 = *reinterpret_cast<const bf16x8*>(&vr[(quad << 3) ^ sw]);
            bf16x8 v1 = *reinterpret_cast<const bf16x8*>(&vr[((quad + 4) << 3) ^ sw]);
            O0[c4] = __builtin_amdgcn_mfma_f32_16x16x32_bf16(paa0, v0, O0[c4], 0, 0, 0);
            O0[c4] = __builtin_amdgcn_mfma_f32_16x16x32_bf16(paa1, v1, O0[c4], 0, 0, 0);
            O1[c4] = __builtin_amdgcn_mfma_f32_16x16x32_bf16(pba0, v0, O1[c4], 0, 0, 0);
            O1[c4] = __builtin_amdgcn_mfma_f32_16x16x32_bf16(pba1, v1, O1[c4], 0, 0, 0);
        }
        __builtin_amdgcn_s_setprio(0);
    };

    STAGE(0, 0);
    for (int it = 0; it < 16; it += 2) {
        __syncthreads();                 // buf0 staged; prior buf1 reads done
        STAGE(it + 1, 1);
        body(0);
        __syncthreads();                 // buf1 staged; buf0 reads done
        if (it + 2 < 16) STAGE(it + 2, 0);
        body(1);
    }
#undef STAGE

    // ---- in-block K-half combine through LDS scratch -----------------------
    __syncthreads();                     // all bodies done; staging LDS free
    float* scr = reinterpret_cast<float*>(SMEM);
    {
        float* myr = scr + w * 2176;     // 32 rows x 68 f32 (272B rows: b128-aligned, conflict-free)
#pragma unroll
        for (int c4 = 0; c4 < 4; ++c4) {
            int dcol = c4 * 16 + l15;
#pragma unroll
            for (int r = 0; r < 4; ++r) {
                myr[(quad * 4 + r) * 68 + dcol] = O0[c4][r];
                myr[(16 + quad * 4 + r) * 68 + dcol] = O1[c4][r];
            }
        }
        if (l15 == 0) {
#pragma unroll
            for (int r = 0; r < 4; ++r) {
                myr[(quad * 4 + r) * 68 + 64] = asum0[r];
                myr[(16 + quad * 4 + r) * 68 + 64] = asum1[r];
            }
        }
    }
    __syncthreads();
    const int b = bh >> 4, h = bh & 15;
    const float* rA = scr + qg * 2176;           // K-half 0 partials for my q-group
    const float* rB = rA + 4 * 2176;             // K-half 1 partials
    const int row = kh * 16 + (lane >> 2);       // each wave finalizes 16 of its group's 32 rows
    const int dq = (lane & 3) * 16;
    const int base = (b * 2048 + (q0w + row)) * 1024 + h * 64;
    const float den = rA[row * 68 + 64] + rB[row * 68 + 64];
    const float inv = 1.f / den;
#pragma unroll
    for (int j = 0; j < 4; ++j) {
        int d = dq + j * 4;
        f32x4 pa = *reinterpret_cast<const f32x4*>(&rA[row * 68 + d]);
        f32x4 pb = *reinterpret_cast<const f32x4*>(&rB[row * 68 + d]);
        float4 fv = *reinterpret_cast<const float4*>(&f[base + d]);
        float o0 = (pa[0] + pb[0]) * inv;
        float o1 = (pa[1] + pb[1]) * inv;
        float o2 = (pa[2] + pb[2]) * inv;
        float o3 = (pa[3] + pb[3]) * inv;
        *reinterpret_cast<float4*>(&attn2_out[base + d]) = make_float4(o0, o1, o2, o3);
        ushort4 pk = make_ushort4(f2bf(o0 + fv.x), f2bf(o1 + fv.y),
                                  f2bf(o2 + fv.z), f2bf(o3 + fv.w));
        *reinterpret_cast<ushort4*>(&fusedb[base + d]) = pk;
    }
}

// ---------------------------------------------------------------------------
// GEMM2: fused(4096,1024) @ WprojT(1024,1024)^T + bias. 128x64 tile,
// grid (16,32)=512 -> 2 blocks/CU, wave 64x32.
// ---------------------------------------------------------------------------
__global__ __launch_bounds__(256) void gemm_proj(const unsigned short* __restrict__ A,
                                                 const unsigned short* __restrict__ Bt,
                                                 const float* __restrict__ bias,
                                                 float* __restrict__ out) {
    __shared__ __align__(16) unsigned short As[8192];
    __shared__ __align__(16) unsigned short Bs[4096];
    const int tid = threadIdx.x;
    const int w = tid >> 6, lane = tid & 63, quad = lane >> 4, l15 = lane & 15;
    const int m0 = blockIdx.y * 128, n0 = blockIdx.x * 64;
    const int wm = (w & 1) * 64, wn = (w >> 1) * 32;
    const int sw = (l15 & 7) << 3;
    f32x4 acc[4][2] = {};
    for (int k0 = 0; k0 < 1024; k0 += 64) {
        __syncthreads();
#pragma unroll
        for (int t = 0; t < 4; ++t) {
            int c = t * 256 + tid;
            int row = c >> 3, jg = ((c & 7) ^ (row & 7)) * 8;
            gl2lds16(&A[(m0 + row) * 1024 + k0 + jg], &As[c * 8]);
            if (t < 2) gl2lds16(&Bt[(n0 + row) * 1024 + k0 + jg], &Bs[c * 8]);
        }
        __syncthreads();
#pragma unroll
        for (int kk = 0; kk < 2; ++kk) {
            bf16x8 af[4], bfr[2];
#pragma unroll
            for (int i = 0; i < 4; ++i)
                af[i] = *reinterpret_cast<const bf16x8*>(
                    &As[(wm + i * 16 + l15) * 64 + ((((kk * 4 + quad) << 3) ^ sw))]);
#pragma unroll
            for (int j = 0; j < 2; ++j)
                bfr[j] = *reinterpret_cast<const bf16x8*>(
                    &Bs[(wn + j * 16 + l15) * 64 + ((((kk * 4 + quad) << 3) ^ sw))]);
#pragma unroll
            for (int i = 0; i < 4; ++i)
#pragma unroll
                for (int j = 0; j < 2; ++j)
                    acc[i][j] = __builtin_amdgcn_mfma_f32_16x16x32_bf16(af[i], bfr[j], acc[i][j], 0, 0, 0);
        }
    }
#pragma unroll
    for (int j = 0; j < 2; ++j) {
        int n = n0 + wn + j * 16 + l15;
        float bv = bias[n];
#pragma unroll
        for (int i = 0; i < 4; ++i)
#pragma unroll
            for (int r = 0; r < 4; ++r) {
                int m = m0 + wm + i * 16 + quad * 4 + r;
                out[m * 1024 + n] = acc[i][j][r] + bv;
            }
    }
}

extern "C" void kernel_launch(void* const* d_in, const int* in_sizes, int n_in,
                              void* d_out, int out_size, void* d_ws, size_t ws_size,
                              hipStream_t stream) {
    const float* x      = (const float*)d_in[0];
    const float* f      = (const float*)d_in[1];
    const float* W_qkv  = (const float*)d_in[2];
    const float* W_proj = (const float*)d_in[3];
    const float* b_proj = (const float*)d_in[4];
    float* out   = (float*)d_out;
    float* attn2 = out + OUT1_OFF;

    char* ws = (char*)d_ws;
    unsigned short* xb     = (unsigned short*)(ws);                 //  8 MiB
    unsigned short* wqkvT  = (unsigned short*)(ws + 8388608);       //  6 MiB (3072,1024)
    unsigned short* wprojT = (unsigned short*)(ws + 14680064);      //  2 MiB (1024,1024)
    unsigned short* qb     = (unsigned short*)(ws + 16777216);      //  8 MiB (B,H,N,D)
    unsigned short* kb     = (unsigned short*)(ws + 25165824);      //  8 MiB (B,H,N,D)
    unsigned short* vtb    = (unsigned short*)(ws + 33554432);      //  8 MiB (B,H,kblk,D,slot)
    unsigned short* fusedb = (unsigned short*)(ws + 41943040);      //  8 MiB (B*N,C)

    prep<<<5120, 256, 0, stream>>>(x, W_qkv, W_proj, xb, wqkvT, wprojT);
    gemm_qkv<<<dim3(24, 32), 256, 0, stream>>>(xb, wqkvT, qb, kb, vtb);
    attn_kernel<<<dim3(32, 16), 512, 0, stream>>>(qb, kb, vtb, f, attn2, fusedb);
    gemm_proj<<<dim3(16, 32), 256, 0, stream>>>(fusedb, wprojT, b_proj, out);
}

// Round 3
// 175.750 us; speedup vs baseline: 1.0919x; 1.0642x over previous
//
#include <hip/hip_runtime.h>
#include <hip/hip_bf16.h>

// B=2, N=2048, C=1024, H=16, D=64, SCALE=0.125
// out0 = (attn(x)+f) @ W_proj + b_proj ; out1 = attn2gcn
#define OUT1_OFF 4194304
#define QSCALE 0.1803368801111204f   // 0.125 * log2(e)

typedef __attribute__((ext_vector_type(8))) short bf16x8;
typedef __attribute__((ext_vector_type(4))) float f32x4;

__device__ __forceinline__ unsigned short f2bf(float x) {
    unsigned u = __float_as_uint(x);
    u += 0x7FFFu + ((u >> 16) & 1u);
    return (unsigned short)(u >> 16);
}

// async global->LDS, 16B per lane. dst must be base + lane*16 (contiguous).
__device__ __forceinline__ void gl2lds16(const unsigned short* g, unsigned short* l) {
    __builtin_amdgcn_global_load_lds(
        (const __attribute__((address_space(1))) unsigned int*)g,
        (__attribute__((address_space(3))) unsigned int*)l, 16, 0, 0);
}

// ---------------------------------------------------------------------------
// prep: region-branched fused converts (x -> bf16; W_qkv, W_proj -> transposed bf16)
// ---------------------------------------------------------------------------
__global__ __launch_bounds__(256) void prep(const float* __restrict__ x,
                                            const float* __restrict__ Wqkv,
                                            const float* __restrict__ Wproj,
                                            unsigned short* __restrict__ xb,
                                            unsigned short* __restrict__ wqkvT,
                                            unsigned short* __restrict__ wprojT) {
    __shared__ float T[64][65];
    const int bid = blockIdx.x, tid = threadIdx.x;
    if (bid < 4096) {
        int i = bid * 256 + tid;
        float4 v = reinterpret_cast<const float4*>(x)[i];
        ushort4 o = make_ushort4(f2bf(v.x), f2bf(v.y), f2bf(v.z), f2bf(v.w));
        reinterpret_cast<ushort4*>(xb)[i] = o;
        return;
    }
    const float* in; unsigned short* out; int Nd, bx, by;
    if (bid < 4864) { int t = bid - 4096; in = Wqkv;  out = wqkvT;  Nd = 3072; bx = t % 48; by = t / 48; }
    else            { int t = bid - 4864; in = Wproj; out = wprojT; Nd = 1024; bx = t % 16; by = t / 16; }
    const int Kd = 1024;
    const int r0 = by * 64, c0 = bx * 64;
    const int tr = tid >> 3, tc = (tid & 7) * 8;
#pragma unroll
    for (int rr = 0; rr < 64; rr += 32) {
        const float4* p = reinterpret_cast<const float4*>(&in[(r0 + tr + rr) * Nd + c0 + tc]);
        float4 v0 = p[0], v1 = p[1];
        T[tr + rr][tc + 0] = v0.x; T[tr + rr][tc + 1] = v0.y;
        T[tr + rr][tc + 2] = v0.z; T[tr + rr][tc + 3] = v0.w;
        T[tr + rr][tc + 4] = v1.x; T[tr + rr][tc + 5] = v1.y;
        T[tr + rr][tc + 6] = v1.z; T[tr + rr][tc + 7] = v1.w;
    }
    __syncthreads();
#pragma unroll
    for (int rr = 0; rr < 64; rr += 32) {
        int orow = tr + rr;
        ushort4 o0 = make_ushort4(f2bf(T[tc + 0][orow]), f2bf(T[tc + 1][orow]),
                                  f2bf(T[tc + 2][orow]), f2bf(T[tc + 3][orow]));
        ushort4 o1 = make_ushort4(f2bf(T[tc + 4][orow]), f2bf(T[tc + 5][orow]),
                                  f2bf(T[tc + 6][orow]), f2bf(T[tc + 7][orow]));
        unsigned short* dst = &out[(c0 + orow) * Kd + r0 + tc];
        *reinterpret_cast<ushort4*>(dst) = o0;
        *reinterpret_cast<ushort4*>(dst + 4) = o1;
    }
}

// ---------------------------------------------------------------------------
// GEMM1 v2: x(4096,1024) @ WqkvT(3072,1024)^T. 128x128 tile, BK=64, 4 waves.
// DOUBLE-BUFFERED staging (64 KB LDS): STAGE(k+1) issued before compute(k),
// drained by the barrier after the compute -> staging latency hidden under
// MFMA instead of fully serialized (was MfmaUtil 19%, all pipes <20%).
// Epilogue transpose scratch aliases the dbuf region after the last barrier.
// ---------------------------------------------------------------------------
__global__ __launch_bounds__(256) void gemm_qkv(const unsigned short* __restrict__ A,
                                                const unsigned short* __restrict__ Bt,
                                                unsigned short* __restrict__ qb,
                                                unsigned short* __restrict__ kb,
                                                unsigned short* __restrict__ vtb) {
    __shared__ __align__(16) unsigned short Sh[32768];   // 64 KB: 2 x (As 16K + Bs 16K)
    const int tid = threadIdx.x;
    const int w = tid >> 6, lane = tid & 63, quad = lane >> 4, l15 = lane & 15;
    const int m0 = blockIdx.y * 128, n0 = blockIdx.x * 128;
    const int wm = (w & 1) * 64, wn = (w >> 1) * 64;
    const int nbase = n0 + wn;
    const int t = nbase >> 10;           // 0=q 1=k 2=v (wave-uniform)
    const bool qk = (t < 2);
    const int sw = (l15 & 7) << 3;
    f32x4 acc[4][4] = {};

#define QKV_STAGE(K0, BUF) do {                                               \
        unsigned short* As_ = &Sh[(BUF) * 16384];                             \
        unsigned short* Bs_ = As_ + 8192;                                     \
        _Pragma("unroll")                                                     \
        for (int tt = 0; tt < 4; ++tt) {                                      \
            int c = tt * 256 + tid;                                           \
            int row = c >> 3, jg = ((c & 7) ^ (row & 7)) * 8;                 \
            gl2lds16(&A[(m0 + row) * 1024 + (K0) + jg], &As_[c * 8]);         \
            gl2lds16(&Bt[(n0 + row) * 1024 + (K0) + jg], &Bs_[c * 8]);        \
        } } while (0)

    auto compute = [&](int buf) {
        const unsigned short* As_ = &Sh[buf * 16384];
        const unsigned short* Bs_ = As_ + 8192;
#pragma unroll
        for (int kk = 0; kk < 2; ++kk) {
            bf16x8 af[4], bfr[4];
#pragma unroll
            for (int i = 0; i < 4; ++i)
                af[i] = *reinterpret_cast<const bf16x8*>(
                    &As_[(wm + i * 16 + l15) * 64 + ((((kk * 4 + quad) << 3) ^ sw))]);
#pragma unroll
            for (int j = 0; j < 4; ++j)
                bfr[j] = *reinterpret_cast<const bf16x8*>(
                    &Bs_[(wn + j * 16 + l15) * 64 + ((((kk * 4 + quad) << 3) ^ sw))]);
            if (qk) {   // D[row=d, col=tok]
#pragma unroll
                for (int i = 0; i < 4; ++i)
#pragma unroll
                    for (int j = 0; j < 4; ++j)
                        acc[i][j] = __builtin_amdgcn_mfma_f32_16x16x32_bf16(bfr[j], af[i], acc[i][j], 0, 0, 0);
            } else {    // D[row=tok, col=d]
#pragma unroll
                for (int i = 0; i < 4; ++i)
#pragma unroll
                    for (int j = 0; j < 4; ++j)
                        acc[i][j] = __builtin_amdgcn_mfma_f32_16x16x32_bf16(af[i], bfr[j], acc[i][j], 0, 0, 0);
            }
        }
    };

    QKV_STAGE(0, 0);
    for (int k0 = 0; k0 < 1024; k0 += 128) {
        __syncthreads();                 // buf0 staged (vmcnt drained); prior buf1 reads done
        QKV_STAGE(k0 + 64, 1);           // async loads in flight under compute(0)
        compute(0);
        __syncthreads();                 // buf1 staged; buf0 reads done
        if (k0 + 128 < 1024) QKV_STAGE(k0 + 128, 0);
        compute(1);
    }
#undef QKV_STAGE
    __syncthreads();                     // staging LDS reusable as scratch
    unsigned short* scr = Sh + w * 4608; // 64 rows x 72 ush (stride 144B, conflict-free)
    const int mb = m0 + wm;
    const int b = mb >> 11;
    const int h = (nbase & 1023) >> 6;
    const float sc = (t == 0) ? QSCALE : 1.f;
    if (qk) {
        // acc[i][j][r]: tok_local = i*16+l15 ; d = j*16+quad*4+r (4 consecutive d)
#pragma unroll
        for (int i = 0; i < 4; ++i) {
            int row = i * 16 + l15;
#pragma unroll
            for (int j = 0; j < 4; ++j) {
                unsigned short h0 = f2bf(acc[i][j][0] * sc), h1 = f2bf(acc[i][j][1] * sc);
                unsigned short h2 = f2bf(acc[i][j][2] * sc), h3 = f2bf(acc[i][j][3] * sc);
                uint2 pk = make_uint2((unsigned)h0 | ((unsigned)h1 << 16),
                                      (unsigned)h2 | ((unsigned)h3 << 16));
                *reinterpret_cast<uint2*>(&scr[row * 72 + j * 16 + quad * 4]) = pk;
            }
        }
        asm volatile("s_waitcnt lgkmcnt(0)" ::: "memory");
        unsigned short* dst = (t == 0 ? qb : kb) + (((b * 16 + h) * 2048) + (mb & 2047)) * 64;
#pragma unroll
        for (int p = 0; p < 8; ++p) {
            int idx = p * 64 + lane;
            *reinterpret_cast<uint4*>(&dst[idx * 8]) =
                *reinterpret_cast<const uint4*>(&scr[(idx >> 3) * 72 + (idx & 7) * 8]);
        }
    } else {
        // V: scratch [d][slot], slot = key permutation matching attn S^T layout
        const int kblk = (mb & 2047) >> 6;
#pragma unroll
        for (int i = 0; i < 4; ++i) {
            int slot0 = ((i & 2) << 4) | (quad << 3) | ((i & 1) << 2);
#pragma unroll
            for (int j = 0; j < 4; ++j) {
                unsigned short h0 = f2bf(acc[i][j][0]), h1 = f2bf(acc[i][j][1]);
                unsigned short h2 = f2bf(acc[i][j][2]), h3 = f2bf(acc[i][j][3]);
                uint2 pk = make_uint2((unsigned)h0 | ((unsigned)h1 << 16),
                                      (unsigned)h2 | ((unsigned)h3 << 16));
                *reinterpret_cast<uint2*>(&scr[(j * 16 + l15) * 72 + slot0]) = pk;
            }
        }
        asm volatile("s_waitcnt lgkmcnt(0)" ::: "memory");
        unsigned short* vtile = vtb + (((b * 16 + h) * 32) + kblk) * 4096;
#pragma unroll
        for (int p = 0; p < 8; ++p) {
            int idx = p * 64 + lane;
            *reinterpret_cast<uint4*>(&vtile[idx * 8]) =
                *reinterpret_cast<const uint4*>(&scr[(idx >> 3) * 72 + (idx & 7) * 8]);
        }
    }
}

// ---------------------------------------------------------------------------
// Attention v7: grid (32 bh, 16 qtiles) = 512 blocks, 512 thr = 8 waves,
// organized as 4 q-groups x 2 K-halves. Each wave: 32 q rows x 16 K-tiles.
// -> per-wave LDS-read bytes HALVED vs v5 at v5's 16 waves/CU occupancy.
// No-max softmax (pure exp2-sum) => K-halves combine by simple addition in
// LDS scratch (staging buffers reused, 68 KB). Double-buffered staging of
// 4 tiles/step (K,V for both halves). LDS 68 KB -> 2 blocks/CU.
// ---------------------------------------------------------------------------
__global__ __launch_bounds__(512, 4) void attn_kernel(const unsigned short* __restrict__ qb,
                                                      const unsigned short* __restrict__ kb,
                                                      const unsigned short* __restrict__ vtb,
                                                      const float* __restrict__ f,
                                                      float* __restrict__ attn2_out,
                                                      unsigned short* __restrict__ fusedb) {
    __shared__ __align__(16) unsigned char SMEM[69632];  // staging 64K | scratch 8x(32x68 f32)
    unsigned short* S16 = reinterpret_cast<unsigned short*>(SMEM);
    const int tid = threadIdx.x;
    const int w = tid >> 6, lane = tid & 63, quad = lane >> 4, l15 = lane & 15;
    const int qg = w & 3, kh = w >> 2;   // q-group 0..3, K-half 0..1
    const int bh = blockIdx.x;           // bh mod 8 = XCD -> K/V L2-resident per XCD
    const int q0w = blockIdx.y * 128 + qg * 32;
    const unsigned short* qr = &qb[(bh * 2048 + q0w + l15) * 64 + quad * 8];
    bf16x8 ql0 = *reinterpret_cast<const bf16x8*>(qr);
    bf16x8 ql1 = *reinterpret_cast<const bf16x8*>(qr + 32);
    bf16x8 ql2 = *reinterpret_cast<const bf16x8*>(qr + 1024);   // q-half 1: +16 rows
    bf16x8 ql3 = *reinterpret_cast<const bf16x8*>(qr + 1056);
    const unsigned short* kt0 = kb + bh * 131072;
    const unsigned short* vt0 = vtb + bh * 131072;
    const int gu = (((tid & ~7) | ((tid & 7) ^ ((tid >> 3) & 7))) << 3);
    const int sw = (l15 & 7) << 3;
    f32x4 O0[4] = {}, O1[4] = {};
    f32x4 asum0 = {}, asum1 = {};
    bf16x8 ones;
#pragma unroll
    for (int j = 0; j < 8; ++j) ones[j] = (short)0x3F80;   // bf16 1.0

    // stage K,V tiles (IT) for half0 and (16+IT) for half1 into buffer BUF.
    // layout per buf (16384 ush): [K h0][V h0][K h1][V h1], 4096 ush each.
#define STAGE(IT, BUF) do { unsigned short* db_ = &S16[(BUF) * 16384 + tid * 8]; \
        const int go_ = (IT) * 4096 + gu;                                        \
        gl2lds16(kt0 + go_, db_);                                                \
        gl2lds16(vt0 + go_, db_ + 4096);                                         \
        gl2lds16(kt0 + 65536 + go_, db_ + 8192);                                 \
        gl2lds16(vt0 + 65536 + go_, db_ + 12288); } while (0)

    auto body = [&](int buf) {
        const unsigned short* Kb = &S16[buf * 16384 + kh * 8192];
        const unsigned short* Vb = Kb + 4096;
        f32x4 Ta[4], Tb[4];
        __builtin_amdgcn_s_setprio(1);
#pragma unroll
        for (int s = 0; s < 4; ++s) {
            const unsigned short* kr = &Kb[(s * 16 + l15) * 64];
            bf16x8 k0 = *reinterpret_cast<const bf16x8*>(&kr[(quad << 3) ^ sw]);
            bf16x8 k1 = *reinterpret_cast<const bf16x8*>(&kr[((quad + 4) << 3) ^ sw]);
            f32x4 za = {}, zb = {};
            za = __builtin_amdgcn_mfma_f32_16x16x32_bf16(k0, ql0, za, 0, 0, 0);
            za = __builtin_amdgcn_mfma_f32_16x16x32_bf16(k1, ql1, za, 0, 0, 0);
            zb = __builtin_amdgcn_mfma_f32_16x16x32_bf16(k0, ql2, zb, 0, 0, 0);
            zb = __builtin_amdgcn_mfma_f32_16x16x32_bf16(k1, ql3, zb, 0, 0, 0);
            Ta[s] = za; Tb[s] = zb;
        }
        __builtin_amdgcn_s_setprio(0);
        float pa_[4][4], pb_[4][4];
#pragma unroll
        for (int s = 0; s < 4; ++s)
#pragma unroll
            for (int r = 0; r < 4; ++r) {
                pa_[s][r] = __builtin_amdgcn_exp2f(Ta[s][r]);
                pb_[s][r] = __builtin_amdgcn_exp2f(Tb[s][r]);
            }
        uint4 u0, u1, v0u, v1u;
        u0.x = __builtin_amdgcn_perm(__float_as_uint(pa_[0][1]), __float_as_uint(pa_[0][0]), 0x07060302u);
        u0.y = __builtin_amdgcn_perm(__float_as_uint(pa_[0][3]), __float_as_uint(pa_[0][2]), 0x07060302u);
        u0.z = __builtin_amdgcn_perm(__float_as_uint(pa_[1][1]), __float_as_uint(pa_[1][0]), 0x07060302u);
        u0.w = __builtin_amdgcn_perm(__float_as_uint(pa_[1][3]), __float_as_uint(pa_[1][2]), 0x07060302u);
        u1.x = __builtin_amdgcn_perm(__float_as_uint(pa_[2][1]), __float_as_uint(pa_[2][0]), 0x07060302u);
        u1.y = __builtin_amdgcn_perm(__float_as_uint(pa_[2][3]), __float_as_uint(pa_[2][2]), 0x07060302u);
        u1.z = __builtin_amdgcn_perm(__float_as_uint(pa_[3][1]), __float_as_uint(pa_[3][0]), 0x07060302u);
        u1.w = __builtin_amdgcn_perm(__float_as_uint(pa_[3][3]), __float_as_uint(pa_[3][2]), 0x07060302u);
        v0u.x = __builtin_amdgcn_perm(__float_as_uint(pb_[0][1]), __float_as_uint(pb_[0][0]), 0x07060302u);
        v0u.y = __builtin_amdgcn_perm(__float_as_uint(pb_[0][3]), __float_as_uint(pb_[0][2]), 0x07060302u);
        v0u.z = __builtin_amdgcn_perm(__float_as_uint(pb_[1][1]), __float_as_uint(pb_[1][0]), 0x07060302u);
        v0u.w = __builtin_amdgcn_perm(__float_as_uint(pb_[1][3]), __float_as_uint(pb_[1][2]), 0x07060302u);
        v1u.x = __builtin_amdgcn_perm(__float_as_uint(pb_[2][1]), __float_as_uint(pb_[2][0]), 0x07060302u);
        v1u.y = __builtin_amdgcn_perm(__float_as_uint(pb_[2][3]), __float_as_uint(pb_[2][2]), 0x07060302u);
        v1u.z = __builtin_amdgcn_perm(__float_as_uint(pb_[3][1]), __float_as_uint(pb_[3][0]), 0x07060302u);
        v1u.w = __builtin_amdgcn_perm(__float_as_uint(pb_[3][3]), __float_as_uint(pb_[3][2]), 0x07060302u);
        bf16x8 paa0 = __builtin_bit_cast(bf16x8, u0);
        bf16x8 paa1 = __builtin_bit_cast(bf16x8, u1);
        bf16x8 pba0 = __builtin_bit_cast(bf16x8, v0u);
        bf16x8 pba1 = __builtin_bit_cast(bf16x8, v1u);
        asum0 = __builtin_amdgcn_mfma_f32_16x16x32_bf16(paa0, ones, asum0, 0, 0, 0);
        asum0 = __builtin_amdgcn_mfma_f32_16x16x32_bf16(paa1, ones, asum0, 0, 0, 0);
        asum1 = __builtin_amdgcn_mfma_f32_16x16x32_bf16(pba0, ones, asum1, 0, 0, 0);
        asum1 = __builtin_amdgcn_mfma_f32_16x16x32_bf16(pba1, ones, asum1, 0, 0, 0);
        __builtin_amdgcn_s_setprio(1);
#pragma unroll
        for (int c4 = 0; c4 < 4; ++c4) {
            const unsigned short* vr = &Vb[(c4 * 16 + l15) * 64];
            bf16x8 v0 = *reinterpret_cast<const bf16x8*>(&vr[(quad << 3) ^ sw]);
            bf16x8 v1 = *reinterpret_cast<const bf16x8*>(&vr[((quad + 4) << 3) ^ sw]);
            O0[c4] = __builtin_amdgcn_mfma_f32_16x16x32_bf16(paa0, v0, O0[c4], 0, 0, 0);
            O0[c4] = __builtin_amdgcn_mfma_f32_16x16x32_bf16(paa1, v1, O0[c4], 0, 0, 0);
            O1[c4] = __builtin_amdgcn_mfma_f32_16x16x32_bf16(pba0, v0, O1[c4], 0, 0, 0);
            O1[c4] = __builtin_amdgcn_mfma_f32_16x16x32_bf16(pba1, v1, O1[c4], 0, 0, 0);
        }
        __builtin_amdgcn_s_setprio(0);
    };

    STAGE(0, 0);
    for (int it = 0; it < 16; it += 2) {
        __syncthreads();                 // buf0 staged; prior buf1 reads done
        STAGE(it + 1, 1);
        body(0);
        __syncthreads();                 // buf1 staged; buf0 reads done
        if (it + 2 < 16) STAGE(it + 2, 0);
        body(1);
    }
#undef STAGE

    // ---- in-block K-half combine through LDS scratch -----------------------
    __syncthreads();                     // all bodies done; staging LDS free
    float* scr = reinterpret_cast<float*>(SMEM);
    {
        float* myr = scr + w * 2176;     // 32 rows x 68 f32 (272B rows: b128-aligned, conflict-free)
#pragma unroll
        for (int c4 = 0; c4 < 4; ++c4) {
            int dcol = c4 * 16 + l15;
#pragma unroll
            for (int r = 0; r < 4; ++r) {
                myr[(quad * 4 + r) * 68 + dcol] = O0[c4][r];
                myr[(16 + quad * 4 + r) * 68 + dcol] = O1[c4][r];
            }
        }
        if (l15 == 0) {
#pragma unroll
            for (int r = 0; r < 4; ++r) {
                myr[(quad * 4 + r) * 68 + 64] = asum0[r];
                myr[(16 + quad * 4 + r) * 68 + 64] = asum1[r];
            }
        }
    }
    __syncthreads();
    const int b = bh >> 4, h = bh & 15;
    const float* rA = scr + qg * 2176;           // K-half 0 partials for my q-group
    const float* rB = rA + 4 * 2176;             // K-half 1 partials
    const int row = kh * 16 + (lane >> 2);       // each wave finalizes 16 of its group's 32 rows
    const int dq = (lane & 3) * 16;
    const int base = (b * 2048 + (q0w + row)) * 1024 + h * 64;
    const float den = rA[row * 68 + 64] + rB[row * 68 + 64];
    const float inv = 1.f / den;
#pragma unroll
    for (int j = 0; j < 4; ++j) {
        int d = dq + j * 4;
        f32x4 pa = *reinterpret_cast<const f32x4*>(&rA[row * 68 + d]);
        f32x4 pb = *reinterpret_cast<const f32x4*>(&rB[row * 68 + d]);
        float4 fv = *reinterpret_cast<const float4*>(&f[base + d]);
        float o0 = (pa[0] + pb[0]) * inv;
        float o1 = (pa[1] + pb[1]) * inv;
        float o2 = (pa[2] + pb[2]) * inv;
        float o3 = (pa[3] + pb[3]) * inv;
        *reinterpret_cast<float4*>(&attn2_out[base + d]) = make_float4(o0, o1, o2, o3);
        ushort4 pk = make_ushort4(f2bf(o0 + fv.x), f2bf(o1 + fv.y),
                                  f2bf(o2 + fv.z), f2bf(o3 + fv.w));
        *reinterpret_cast<ushort4*>(&fusedb[base + d]) = pk;
    }
}

// ---------------------------------------------------------------------------
// GEMM2 v2: fused(4096,1024) @ WprojT(1024,1024)^T + bias. 128x64 tile,
// grid (16,32)=512 -> 2 blocks/CU. DOUBLE-BUFFERED staging (48 KB LDS),
// same overlap pattern as gemm_qkv v2.
// ---------------------------------------------------------------------------
__global__ __launch_bounds__(256) void gemm_proj(const unsigned short* __restrict__ A,
                                                 const unsigned short* __restrict__ Bt,
                                                 const float* __restrict__ bias,
                                                 float* __restrict__ out) {
    __shared__ __align__(16) unsigned short Sh[24576];  // 48 KB: 2 x (As 16K + Bs 8K)
    const int tid = threadIdx.x;
    const int w = tid >> 6, lane = tid & 63, quad = lane >> 4, l15 = lane & 15;
    const int m0 = blockIdx.y * 128, n0 = blockIdx.x * 64;
    const int wm = (w & 1) * 64, wn = (w >> 1) * 32;
    const int sw = (l15 & 7) << 3;
    f32x4 acc[4][2] = {};

#define PROJ_STAGE(K0, BUF) do {                                              \
        unsigned short* As_ = &Sh[(BUF) * 12288];                             \
        unsigned short* Bs_ = As_ + 8192;                                     \
        _Pragma("unroll")                                                     \
        for (int tt = 0; tt < 4; ++tt) {                                      \
            int c = tt * 256 + tid;                                           \
            int row = c >> 3, jg = ((c & 7) ^ (row & 7)) * 8;                 \
            gl2lds16(&A[(m0 + row) * 1024 + (K0) + jg], &As_[c * 8]);         \
            if (tt < 2) gl2lds16(&Bt[(n0 + row) * 1024 + (K0) + jg], &Bs_[c * 8]); \
        } } while (0)

    auto compute = [&](int buf) {
        const unsigned short* As_ = &Sh[buf * 12288];
        const unsigned short* Bs_ = As_ + 8192;
#pragma unroll
        for (int kk = 0; kk < 2; ++kk) {
            bf16x8 af[4], bfr[2];
#pragma unroll
            for (int i = 0; i < 4; ++i)
                af[i] = *reinterpret_cast<const bf16x8*>(
                    &As_[(wm + i * 16 + l15) * 64 + ((((kk * 4 + quad) << 3) ^ sw))]);
#pragma unroll
            for (int j = 0; j < 2; ++j)
                bfr[j] = *reinterpret_cast<const bf16x8*>(
                    &Bs_[(wn + j * 16 + l15) * 64 + ((((kk * 4 + quad) << 3) ^ sw))]);
#pragma unroll
            for (int i = 0; i < 4; ++i)
#pragma unroll
                for (int j = 0; j < 2; ++j)
                    acc[i][j] = __builtin_amdgcn_mfma_f32_16x16x32_bf16(af[i], bfr[j], acc[i][j], 0, 0, 0);
        }
    };

    PROJ_STAGE(0, 0);
    for (int k0 = 0; k0 < 1024; k0 += 128) {
        __syncthreads();                 // buf0 staged; prior buf1 reads done
        PROJ_STAGE(k0 + 64, 1);
        compute(0);
        __syncthreads();                 // buf1 staged; buf0 reads done
        if (k0 + 128 < 1024) PROJ_STAGE(k0 + 128, 0);
        compute(1);
    }
#undef PROJ_STAGE

#pragma unroll
    for (int j = 0; j < 2; ++j) {
        int n = n0 + wn + j * 16 + l15;
        float bv = bias[n];
#pragma unroll
        for (int i = 0; i < 4; ++i)
#pragma unroll
            for (int r = 0; r < 4; ++r) {
                int m = m0 + wm + i * 16 + quad * 4 + r;
                out[m * 1024 + n] = acc[i][j][r] + bv;
            }
    }
}

extern "C" void kernel_launch(void* const* d_in, const int* in_sizes, int n_in,
                              void* d_out, int out_size, void* d_ws, size_t ws_size,
                              hipStream_t stream) {
    const float* x      = (const float*)d_in[0];
    const float* f      = (const float*)d_in[1];
    const float* W_qkv  = (const float*)d_in[2];
    const float* W_proj = (const float*)d_in[3];
    const float* b_proj = (const float*)d_in[4];
    float* out   = (float*)d_out;
    float* attn2 = out + OUT1_OFF;

    char* ws = (char*)d_ws;
    unsigned short* xb     = (unsigned short*)(ws);                 //  8 MiB
    unsigned short* wqkvT  = (unsigned short*)(ws + 8388608);       //  6 MiB (3072,1024)
    unsigned short* wprojT = (unsigned short*)(ws + 14680064);      //  2 MiB (1024,1024)
    unsigned short* qb     = (unsigned short*)(ws + 16777216);      //  8 MiB (B,H,N,D)
    unsigned short* kb     = (unsigned short*)(ws + 25165824);      //  8 MiB (B,H,N,D)
    unsigned short* vtb    = (unsigned short*)(ws + 33554432);      //  8 MiB (B,H,kblk,D,slot)
    unsigned short* fusedb = (unsigned short*)(ws + 41943040);      //  8 MiB (B*N,C)

    prep<<<5120, 256, 0, stream>>>(x, W_qkv, W_proj, xb, wqkvT, wprojT);
    gemm_qkv<<<dim3(24, 32), 256, 0, stream>>>(xb, wqkvT, qb, kb, vtb);
    attn_kernel<<<dim3(32, 16), 512, 0, stream>>>(qb, kb, vtb, f, attn2, fusedb);
    gemm_proj<<<dim3(16, 32), 256, 0, stream>>>(fusedb, wprojT, b_proj, out);
}